// Round 7
// baseline (165.725 us; speedup 1.0000x reference)
//
#include <hip/hip_runtime.h>
#include <hip/hip_bf16.h>

constexpr int B  = 8;
constexpr int N  = 1024;
constexpr int FI = 64;
constexpr int FO = 128;
constexpr int NH = 4;
constexpr float LOG2E = 1.4426950408889634f;

using short8 = __attribute__((ext_vector_type(8))) short;
using f32x4  = __attribute__((ext_vector_type(4))) float;

union I8 { int4 v[2]; int s[8]; };
union F8 { float4 v[2]; float s[8]; };

__device__ __forceinline__ unsigned bfpack(float a, float b) {
  __hip_bfloat162 r = __float22bfloat162_rn(make_float2(a, b));
  union { __hip_bfloat162 h; unsigned u; } c; c.h = r; return c.u;
}
__device__ __forceinline__ float bf2f(unsigned short u) {
  union { unsigned int b; float f; } c; c.b = (unsigned int)u << 16; return c.f;
}

// ---------------------------------------------------------------------------
// Kernel 0: mew[i][j] = adj ? bf16(ew) : -0.0  (sign bit = mask).
// ---------------------------------------------------------------------------
__global__ __launch_bounds__(256) void gat_mask(
    const int* __restrict__ adj, const float* __restrict__ ew,
    unsigned short* __restrict__ mew) {
  const size_t base = ((size_t)blockIdx.x * 256 + threadIdx.x) * 8;
  I8 aj; aj.v[0] = *(const int4*)(adj + base); aj.v[1] = *(const int4*)(adj + base + 4);
  F8 e;  e.v[0]  = *(const float4*)(ew + base); e.v[1]  = *(const float4*)(ew + base + 4);
  union { unsigned short u[8]; uint4 v; } o;
  #pragma unroll
  for (int u = 0; u < 8; ++u) {
    __hip_bfloat16 hb = __float2bfloat16(e.s[u]);
    unsigned short bits = *reinterpret_cast<unsigned short*>(&hb);
    o.u[u] = aj.s[u] ? bits : (unsigned short)0x8000;   // -0.0 when masked
  }
  *(uint4*)(mew + base) = o.v;
}

// ---------------------------------------------------------------------------
// Kernel 1: h = x@W. Emits es (row-major) + edt transposed [b][h][j] (both
// pre-scaled by log2e), and h transposed bf16 hi/lo: h_t[b][f][j].
// ---------------------------------------------------------------------------
__global__ __launch_bounds__(256, 2) void gat_proj(
    const float* __restrict__ x, const float* __restrict__ W,
    const float* __restrict__ a,
    unsigned short* __restrict__ h_hi, unsigned short* __restrict__ h_lo,
    float* __restrict__ es, float* __restrict__ edt) {
  __shared__ float xs[16 * FI];
  const int t = threadIdx.x;
  const int row0 = blockIdx.x * 16;
  for (int i = t; i < 16 * FI; i += 256) xs[i] = x[row0 * FI + i];
  const int f  = t & 127;
  const int rh = t >> 7;
  float wc[FI];
  #pragma unroll
  for (int k = 0; k < FI; ++k) wc[k] = W[k * FO + f];
  const int hh = f >> 5, d = f & 31;
  const float a_s = a[hh * 64 + d] * LOG2E;
  const float a_d = a[hh * 64 + 32 + d] * LOG2E;
  __syncthreads();
  float acc8[8];
  #pragma unroll
  for (int r = 0; r < 8; ++r) {
    const int lr = rh * 8 + r;
    const float4* xr = (const float4*)(xs + lr * FI);
    float acc = 0.f;
    #pragma unroll
    for (int kq = 0; kq < FI / 4; ++kq) {
      const float4 xv = xr[kq];
      acc += xv.x * wc[4*kq] + xv.y * wc[4*kq+1] + xv.z * wc[4*kq+2] + xv.w * wc[4*kq+3];
    }
    acc8[r] = acc;
    float ps = acc * a_s, pd = acc * a_d;
    #pragma unroll
    for (int off = 16; off; off >>= 1) {
      ps += __shfl_xor(ps, off, 64);
      pd += __shfl_xor(pd, off, 64);
    }
    const int row = row0 + lr;
    if (d == 0) {
      es[row * NH + hh] = ps;
      edt[((size_t)((row >> 10) * NH + hh)) * N + (row & 1023)] = pd;
    }
  }
  const int bb = row0 >> 10;
  const int jl = (row0 & 1023) + rh * 8;
  union { unsigned short u16[8]; uint4 v; } hi, lo;
  #pragma unroll
  for (int r = 0; r < 8; ++r) {
    __hip_bfloat16 hb = __float2bfloat16(acc8[r]);
    hi.u16[r] = *reinterpret_cast<unsigned short*>(&hb);
    float res = acc8[r] - __bfloat162float(hb);
    __hip_bfloat16 lb = __float2bfloat16(res);
    lo.u16[r] = *reinterpret_cast<unsigned short*>(&lb);
  }
  const size_t base = ((size_t)(bb * FO + f)) * N + jl;
  *(uint4*)(h_hi + base) = hi.v;
  *(uint4*)(h_lo + base) = lo.v;
}

// ---------------------------------------------------------------------------
// Kernel 1b: denominators. 2048 blocks (8/CU, 32 waves/CU), 4 rows/block,
// one wave per row. Pure load->exp->accumulate, shuffle-reduce, write inv.
// ---------------------------------------------------------------------------
__global__ __launch_bounds__(256, 8) void gat_denom(
    const float* __restrict__ es, const float* __restrict__ edt,
    const unsigned short* __restrict__ mew, float* __restrict__ dinv) {
  const int t  = threadIdx.x;
  const int b  = blockIdx.x & 7;
  const int i0 = (blockIdx.x >> 3) << 2;     // 4 rows/block
  const int il = t >> 6, jq = t & 63;
  const int gi = i0 + il;
  float esv[4];
  { const float4 e4 = *(const float4*)(es + ((size_t)b * N + gi) * NH);
    esv[0] = e4.x; esv[1] = e4.y; esv[2] = e4.z; esv[3] = e4.w; }
  float dpart[4] = {0.f, 0.f, 0.f, 0.f};
  #pragma unroll 2
  for (int c = 0; c < 8; ++c) {
    const int jb = c * 128 + jq * 2;
    union { unsigned v; unsigned short u[2]; } mwu;
    mwu.v = *(const unsigned*)(mew + (size_t)gi * N + jb);
    float edh[4][2];
    #pragma unroll
    for (int h = 0; h < 4; ++h) {
      const float2 e2 = *(const float2*)(edt + ((size_t)(b * NH + h)) * N + jb);
      edh[h][0] = e2.x; edh[h][1] = e2.y;
    }
    #pragma unroll
    for (int u = 0; u < 2; ++u) {
      const float sgn = (mwu.u[u] >> 15) ? 0.f : 1.f;
      #pragma unroll
      for (int h = 0; h < 4; ++h) {
        float e = esv[h] + edh[h][u];
        e = fmaxf(e, 0.2f * e);
        dpart[h] = fmaf(__builtin_amdgcn_exp2f(e), sgn, dpart[h]);
      }
    }
  }
  #pragma unroll
  for (int h = 0; h < 4; ++h) {
    float v = dpart[h];
    v += __shfl_xor(v, 1, 64);  v += __shfl_xor(v, 2, 64);
    v += __shfl_xor(v, 4, 64);  v += __shfl_xor(v, 8, 64);
    v += __shfl_xor(v, 16, 64); v += __shfl_xor(v, 32, 64);
    dpart[h] = v;
  }
  if (jq == 0) {
    float4 r;
    r.x = dpart[0] > 0.f ? 1.0f / dpart[0] : 0.f;
    r.y = dpart[1] > 0.f ? 1.0f / dpart[1] : 0.f;
    r.z = dpart[2] > 0.f ? 1.0f / dpart[2] : 0.f;
    r.w = dpart[3] > 0.f ? 1.0f / dpart[3] : 0.f;
    *(float4*)(dinv + ((size_t)b * N + gi) * NH) = r;
  }
}

// ---------------------------------------------------------------------------
// Kernel 2: fused attention + avg. 512 threads, 8-row i-tiles -> 1024 blocks
// (4 blocks/CU). A-frag rows 8-15 zero-filled once (MFMA waste is cheap).
// Double-buffered chunk loop, 1 barrier/chunk:
//  P2(c): MFMA from pew[c&1] (bf16 p*|mew| unnormalized), B from global h_t.
//  P1(c+1): 8 exps/thread; avg row = 0.25*sum_h(p*|mew|*inv) fp32;
//           pack p*|mew| bf16 -> pew[(c+1)&1]. Masked: |mew|=0 zeroes all.
// Epilogue: out = (acc_hi + acc_lo) * dinv (fp32), rows 0-7 only.
// ---------------------------------------------------------------------------
__global__ __launch_bounds__(512, 8) void gat_attn(
    const unsigned short* __restrict__ h_hi, const unsigned short* __restrict__ h_lo,
    const float* __restrict__ es, const float* __restrict__ edt,
    const unsigned short* __restrict__ mew, const float* __restrict__ dinv,
    float* __restrict__ out, float* __restrict__ avg) {
  __shared__ unsigned short pew[2][4 * 2048];   // double-buffered A-frag tiles
  __shared__ float dvl[32];
  const int t  = threadIdx.x;
  const int b  = blockIdx.x & 7;
  const int i0 = (blockIdx.x >> 3) << 3;        // 8 rows/block
  // P1 ids: one wave per row (il = wave), 64 j-lanes x 2 j each
  const int il = t >> 6, jq = t & 63;
  const int gi = i0 + il;
  float esv[4], inv4[4];
  { const float4 e4 = *(const float4*)(es + ((size_t)b * N + gi) * NH);
    esv[0] = e4.x; esv[1] = e4.y; esv[2] = e4.z; esv[3] = e4.w; }
  { const float4 d4 = *(const float4*)(dinv + ((size_t)b * N + gi) * NH);
    inv4[0] = d4.x; inv4[1] = d4.y; inv4[2] = d4.z; inv4[3] = d4.w; }
  if (t < 32) dvl[t] = dinv[((size_t)b * N + i0) * NH + t];
  // P2 ids
  const int lane = t & 63, wave = t >> 6;
  const int hh = wave & 3, nt2 = wave >> 2;
  const int m = lane & 15, kq = lane >> 4;
  f32x4 acch = {0.f,0.f,0.f,0.f}, accl = {0.f,0.f,0.f,0.f};

  // zero-init both pew buffers (covers the always-zero A rows 8-15)
  {
    uint4 z = {0,0,0,0};
    uint4* p = (uint4*)&pew[0][0];
    #pragma unroll
    for (int k = 0; k < 4; ++k) p[t + k * 512] = z;
  }

  auto p1_step = [&](int c, int buf) {
    const int jb = c * 128 + jq * 2;
    union { unsigned v; unsigned short u[2]; } mwu;
    mwu.v = *(const unsigned*)(mew + (size_t)gi * N + jb);
    float edh[4][2];
    #pragma unroll
    for (int h = 0; h < 4; ++h) {
      const float2 e2 = *(const float2*)(edt + ((size_t)(b * NH + h)) * N + jb);
      edh[h][0] = e2.x; edh[h][1] = e2.y;
    }
    float pw[4][2];
    float2 r;
    float* rp = &r.x;
    #pragma unroll
    for (int u = 0; u < 2; ++u) {
      const float mfa = bf2f((unsigned short)(mwu.u[u] & 0x7fff));
      float sv = 0.f;
      #pragma unroll
      for (int h = 0; h < 4; ++h) {
        float e = esv[h] + edh[h][u];
        e = fmaxf(e, 0.2f * e);
        const float p = __builtin_amdgcn_exp2f(e);
        pw[h][u] = p * mfa;                // masked: |mew|=0 -> 0
        sv += p * inv4[h];
      }
      rp[u] = 0.25f * mfa * sv;
    }
    *(float2*)(avg + ((size_t)b * N + gi) * N + jb) = r;
    const int g = jq >> 2;
    const int o = ((g * 16 + il) ^ (g & 7)) * 8 + 2 * (jq & 3);
    #pragma unroll
    for (int h = 0; h < 4; ++h)
      *(unsigned*)(pew[buf] + h * 2048 + o) = bfpack(pw[h][0], pw[h][1]);
  };
  auto p2_step = [&](int c, int buf) {
    const int j0 = c * 128;
    #pragma unroll
    for (int ks = 0; ks < 4; ++ks) {
      const int g2 = ks * 4 + kq;
      const int o2 = ((g2 * 16 + m) ^ (g2 & 7)) * 8;
      short8 afr;
      { uint4 tmp = *(const uint4*)(pew[buf] + hh * 2048 + o2);
        __builtin_memcpy(&afr, &tmp, 16); }
      const int jc = j0 + ks * 32 + kq * 8;
      const size_t boff = ((size_t)(b * FO + hh * 32 + nt2 * 16 + m)) * N + jc;
      const short8 bhi = *(const short8*)(h_hi + boff);
      const short8 blo = *(const short8*)(h_lo + boff);
      acch = __builtin_amdgcn_mfma_f32_16x16x32_bf16(afr, bhi, acch, 0, 0, 0);
      accl = __builtin_amdgcn_mfma_f32_16x16x32_bf16(afr, blo, accl, 0, 0, 0);
    }
  };

  __syncthreads();          // zero-fill + dvl visible
  p1_step(0, 0);
  __syncthreads();
  for (int c = 0; c < 8; ++c) {
    if (c + 1 < 8) p1_step(c + 1, (c + 1) & 1);
    p2_step(c, c & 1);
    if (c + 1 < 8) __syncthreads();
  }

  // ---- epilogue: rows 0-7 only (A rows 8-15 are zero) ----
  if (kq < 2) {
    #pragma unroll
    for (int reg = 0; reg < 4; ++reg) {
      const int row = kq * 4 + reg;              // D: col=lane&15, row=quad*4+reg
      const float inv = dvl[row * NH + hh];
      out[((size_t)b * N + i0 + row) * FO + hh * 32 + nt2 * 16 + m]
          = (acch[reg] + accl[reg]) * inv;
    }
  }
}

// ---------------------------------------------------------------------------
extern "C" void kernel_launch(void* const* d_in, const int* in_sizes, int n_in,
                              void* d_out, int out_size, void* d_ws, size_t ws_size,
                              hipStream_t stream) {
  const float* x   = (const float*)d_in[0];
  const int*   adj = (const int*)d_in[1];
  const float* ewt = (const float*)d_in[2];
  const float* W   = (const float*)d_in[3];
  const float* a   = (const float*)d_in[4];

  float* out = (float*)d_out;                  // [B,N,128]
  float* avg = out + (size_t)B * N * FO;       // [B,N,N]

  unsigned short* hhi = (unsigned short*)d_ws;        // [B*FO, N] bf16, 2 MB
  unsigned short* hlo = hhi + (size_t)B * FO * N;     // residual, 2 MB
  unsigned short* mew = hlo + (size_t)B * FO * N;     // [N,N] bf16 masked, 2 MB
  float* es   = (float*)(mew + (size_t)N * N);        // [B*N, 4]
  float* edt  = es + (size_t)B * N * NH;              // [B, 4, N]
  float* dinv = edt + (size_t)B * NH * N;             // [B*N, 4]

  gat_mask<<<(N * N) / 2048, 256, 0, stream>>>(adj, ewt, mew);
  gat_proj<<<(B * N) / 16, 256, 0, stream>>>(x, W, a, hhi, hlo, es, edt);
  gat_denom<<<B * (N / 4), 256, 0, stream>>>(es, edt, mew, dinv);
  gat_attn<<<B * (N / 8), 512, 0, stream>>>(hhi, hlo, es, edt, mew, dinv, out, avg);
}

// Round 8
// 155.458 us; speedup vs baseline: 1.0660x; 1.0660x over previous
//
#include <hip/hip_runtime.h>
#include <hip/hip_bf16.h>

constexpr int B  = 8;
constexpr int N  = 1024;
constexpr int FI = 64;
constexpr int FO = 128;
constexpr int NH = 4;
constexpr float LOG2E = 1.4426950408889634f;

using short8 = __attribute__((ext_vector_type(8))) short;
using f32x4  = __attribute__((ext_vector_type(4))) float;

union I8 { int4 v[2]; int s[8]; };
union F8 { float4 v[2]; float s[8]; };

__device__ __forceinline__ unsigned bfpack(float a, float b) {
  __hip_bfloat162 r = __float22bfloat162_rn(make_float2(a, b));
  union { __hip_bfloat162 h; unsigned u; } c; c.h = r; return c.u;
}
__device__ __forceinline__ float bf2f(unsigned short u) {
  union { unsigned int b; float f; } c; c.b = (unsigned int)u << 16; return c.f;
}

// ---------------------------------------------------------------------------
// Kernel 0: mew[i][j] = adj ? bf16(ew) : -0.0  (sign bit = mask).
// ---------------------------------------------------------------------------
__global__ __launch_bounds__(256) void gat_mask(
    const int* __restrict__ adj, const float* __restrict__ ew,
    unsigned short* __restrict__ mew) {
  const size_t base = ((size_t)blockIdx.x * 256 + threadIdx.x) * 8;
  I8 aj; aj.v[0] = *(const int4*)(adj + base); aj.v[1] = *(const int4*)(adj + base + 4);
  F8 e;  e.v[0]  = *(const float4*)(ew + base); e.v[1]  = *(const float4*)(ew + base + 4);
  union { unsigned short u[8]; uint4 v; } o;
  #pragma unroll
  for (int u = 0; u < 8; ++u) {
    __hip_bfloat16 hb = __float2bfloat16(e.s[u]);
    unsigned short bits = *reinterpret_cast<unsigned short*>(&hb);
    o.u[u] = aj.s[u] ? bits : (unsigned short)0x8000;   // -0.0 when masked
  }
  *(uint4*)(mew + base) = o.v;
}

// ---------------------------------------------------------------------------
// Kernel 1: h = x@W. Emits es (row-major) + edt transposed [b][h][j] (both
// pre-scaled by log2e), and h transposed bf16 hi/lo: h_t[b][f][j].
// ---------------------------------------------------------------------------
__global__ __launch_bounds__(256, 2) void gat_proj(
    const float* __restrict__ x, const float* __restrict__ W,
    const float* __restrict__ a,
    unsigned short* __restrict__ h_hi, unsigned short* __restrict__ h_lo,
    float* __restrict__ es, float* __restrict__ edt) {
  __shared__ float xs[16 * FI];
  const int t = threadIdx.x;
  const int row0 = blockIdx.x * 16;
  for (int i = t; i < 16 * FI; i += 256) xs[i] = x[row0 * FI + i];
  const int f  = t & 127;
  const int rh = t >> 7;
  float wc[FI];
  #pragma unroll
  for (int k = 0; k < FI; ++k) wc[k] = W[k * FO + f];
  const int hh = f >> 5, d = f & 31;
  const float a_s = a[hh * 64 + d] * LOG2E;
  const float a_d = a[hh * 64 + 32 + d] * LOG2E;
  __syncthreads();
  float acc8[8];
  #pragma unroll
  for (int r = 0; r < 8; ++r) {
    const int lr = rh * 8 + r;
    const float4* xr = (const float4*)(xs + lr * FI);
    float acc = 0.f;
    #pragma unroll
    for (int kq = 0; kq < FI / 4; ++kq) {
      const float4 xv = xr[kq];
      acc += xv.x * wc[4*kq] + xv.y * wc[4*kq+1] + xv.z * wc[4*kq+2] + xv.w * wc[4*kq+3];
    }
    acc8[r] = acc;
    float ps = acc * a_s, pd = acc * a_d;
    #pragma unroll
    for (int off = 16; off; off >>= 1) {
      ps += __shfl_xor(ps, off, 64);
      pd += __shfl_xor(pd, off, 64);
    }
    const int row = row0 + lr;
    if (d == 0) {
      es[row * NH + hh] = ps;
      edt[((size_t)((row >> 10) * NH + hh)) * N + (row & 1023)] = pd;
    }
  }
  const int bb = row0 >> 10;
  const int jl = (row0 & 1023) + rh * 8;
  union { unsigned short u16[8]; uint4 v; } hi, lo;
  #pragma unroll
  for (int r = 0; r < 8; ++r) {
    __hip_bfloat16 hb = __float2bfloat16(acc8[r]);
    hi.u16[r] = *reinterpret_cast<unsigned short*>(&hb);
    float res = acc8[r] - __bfloat162float(hb);
    __hip_bfloat16 lb = __float2bfloat16(res);
    lo.u16[r] = *reinterpret_cast<unsigned short*>(&lb);
  }
  const size_t base = ((size_t)(bb * FO + f)) * N + jl;
  *(uint4*)(h_hi + base) = hi.v;
  *(uint4*)(h_lo + base) = lo.v;
}

// ---------------------------------------------------------------------------
// Kernel 1b: denominators + avg, fused. 2048 blocks (8/CU), 4 rows/block,
// one wave per row, no LDS, one implicit wave-sync only. Pass 1: denom;
// shuffle-reduce -> inv (all lanes); Pass 2: recompute p (L1-hot loads),
// write avg. Both passes pure load->exp->acc: fully latency-hidden.
// ---------------------------------------------------------------------------
__global__ __launch_bounds__(256, 8) void gat_denom_avg(
    const float* __restrict__ es, const float* __restrict__ edt,
    const unsigned short* __restrict__ mew, float* __restrict__ dinv,
    float* __restrict__ avg) {
  const int t  = threadIdx.x;
  const int b  = blockIdx.x & 7;
  const int i0 = (blockIdx.x >> 3) << 2;     // 4 rows/block
  const int il = t >> 6, jq = t & 63;
  const int gi = i0 + il;
  float esv[4];
  { const float4 e4 = *(const float4*)(es + ((size_t)b * N + gi) * NH);
    esv[0] = e4.x; esv[1] = e4.y; esv[2] = e4.z; esv[3] = e4.w; }
  // ---- pass 1: denominators ----
  float dpart[4] = {0.f, 0.f, 0.f, 0.f};
  #pragma unroll
  for (int c = 0; c < 4; ++c) {
    const int jb = c * 256 + jq * 4;
    union { uint2 v; unsigned short u[4]; } mw;
    mw.v = *(const uint2*)(mew + (size_t)gi * N + jb);
    float edh[4][4];
    #pragma unroll
    for (int h = 0; h < 4; ++h) {
      const float4 e4 = *(const float4*)(edt + ((size_t)(b * NH + h)) * N + jb);
      edh[h][0] = e4.x; edh[h][1] = e4.y; edh[h][2] = e4.z; edh[h][3] = e4.w;
    }
    #pragma unroll
    for (int u = 0; u < 4; ++u) {
      const float sgn = (mw.u[u] >> 15) ? 0.f : 1.f;
      #pragma unroll
      for (int h = 0; h < 4; ++h) {
        float e = esv[h] + edh[h][u];
        e = fmaxf(e, 0.2f * e);
        dpart[h] = fmaf(__builtin_amdgcn_exp2f(e), sgn, dpart[h]);
      }
    }
  }
  float inv4[4];
  #pragma unroll
  for (int h = 0; h < 4; ++h) {
    float v = dpart[h];
    v += __shfl_xor(v, 1, 64);  v += __shfl_xor(v, 2, 64);
    v += __shfl_xor(v, 4, 64);  v += __shfl_xor(v, 8, 64);
    v += __shfl_xor(v, 16, 64); v += __shfl_xor(v, 32, 64);
    inv4[h] = v > 0.f ? 1.0f / v : 0.f;
  }
  if (jq == 0)
    *(float4*)(dinv + ((size_t)b * N + gi) * NH)
        = make_float4(inv4[0], inv4[1], inv4[2], inv4[3]);
  // ---- pass 2: avg (loads L1-hot from pass 1) ----
  #pragma unroll
  for (int c = 0; c < 4; ++c) {
    const int jb = c * 256 + jq * 4;
    union { uint2 v; unsigned short u[4]; } mw;
    mw.v = *(const uint2*)(mew + (size_t)gi * N + jb);
    float edh[4][4];
    #pragma unroll
    for (int h = 0; h < 4; ++h) {
      const float4 e4 = *(const float4*)(edt + ((size_t)(b * NH + h)) * N + jb);
      edh[h][0] = e4.x; edh[h][1] = e4.y; edh[h][2] = e4.z; edh[h][3] = e4.w;
    }
    float4 r;
    float* rp = &r.x;
    #pragma unroll
    for (int u = 0; u < 4; ++u) {
      const float mfa = bf2f((unsigned short)(mw.u[u] & 0x7fff));
      float sv = 0.f;
      #pragma unroll
      for (int h = 0; h < 4; ++h) {
        float e = esv[h] + edh[h][u];
        e = fmaxf(e, 0.2f * e);
        sv += __builtin_amdgcn_exp2f(e) * inv4[h];
      }
      rp[u] = 0.25f * mfa * sv;            // masked: mfa=0 -> 0
    }
    *(float4*)(avg + ((size_t)b * N + gi) * N + jb) = r;
  }
}

// ---------------------------------------------------------------------------
// Kernel 2: attention out. ZERO LDS, ZERO barriers. 512 thr = 8 waves =
// (head hh x f-half nt2); each lane (m,kq) computes its OWN A-fragment
// (row m, 8 consecutive j) from mew/edt in registers (exp duplicated 2x
// across the nt2 pair - cheap), then feeds MFMA directly. 32 independent
// K-steps: the compiler software-pipelines loads with no sync points.
// Epilogue: out = (acc_hi + acc_lo) * dinv (fp32, R4-proven numerics).
// ---------------------------------------------------------------------------
__global__ __launch_bounds__(512, 4) void gat_attn(
    const unsigned short* __restrict__ h_hi, const unsigned short* __restrict__ h_lo,
    const float* __restrict__ es, const float* __restrict__ edt,
    const unsigned short* __restrict__ mew, const float* __restrict__ dinv,
    float* __restrict__ out) {
  const int t  = threadIdx.x;
  const int b  = blockIdx.x & 7;              // b-clustered for h_t L2 locality
  const int i0 = (blockIdx.x >> 3) << 4;      // 16-row tile
  const int lane = t & 63, wave = t >> 6;
  const int hh = wave & 3, nt2 = wave >> 2;
  const int m = lane & 15, kq = lane >> 4;
  const int gi = i0 + m;
  const float esv = es[((size_t)b * N + gi) * NH + hh];
  const unsigned short* mrow = mew + (size_t)gi * N + kq * 8;
  const float*          erow = edt + ((size_t)(b * NH + hh)) * N + kq * 8;
  const size_t hoff = ((size_t)(b * FO + hh * 32 + nt2 * 16 + m)) * N + kq * 8;
  const unsigned short* hrow_hi = h_hi + hoff;
  const unsigned short* hrow_lo = h_lo + hoff;
  f32x4 acch = {0.f,0.f,0.f,0.f}, accl = {0.f,0.f,0.f,0.f};

  for (int s = 0; s < 32; ++s) {
    const int j = s * 32;
    // A-fragment: p*|mew| for row m, j..j+7 (this lane's exact MFMA slice)
    union { uint4 v; unsigned short u[8]; } mw;
    mw.v = *(const uint4*)(mrow + j);
    const float4 e0 = *(const float4*)(erow + j);
    const float4 e1 = *(const float4*)(erow + j + 4);
    const float ed8[8] = {e0.x,e0.y,e0.z,e0.w,e1.x,e1.y,e1.z,e1.w};
    float pw[8];
    #pragma unroll
    for (int u = 0; u < 8; ++u) {
      float e = esv + ed8[u];
      e = fmaxf(e, 0.2f * e);
      pw[u] = __builtin_amdgcn_exp2f(e)
            * bf2f((unsigned short)(mw.u[u] & 0x7fff));   // masked -> 0
    }
    union { unsigned u[4]; short8 s8; } af;
    af.u[0] = bfpack(pw[0], pw[1]); af.u[1] = bfpack(pw[2], pw[3]);
    af.u[2] = bfpack(pw[4], pw[5]); af.u[3] = bfpack(pw[6], pw[7]);
    const short8 bhi = *(const short8*)(hrow_hi + j);
    const short8 blo = *(const short8*)(hrow_lo + j);
    acch = __builtin_amdgcn_mfma_f32_16x16x32_bf16(af.s8, bhi, acch, 0, 0, 0);
    accl = __builtin_amdgcn_mfma_f32_16x16x32_bf16(af.s8, blo, accl, 0, 0, 0);
  }

  #pragma unroll
  for (int reg = 0; reg < 4; ++reg) {
    const int row = kq * 4 + reg;              // D: col=lane&15, row=quad*4+reg
    const float inv = dinv[((size_t)b * N + i0 + row) * NH + hh];
    out[((size_t)b * N + i0 + row) * FO + hh * 32 + nt2 * 16 + m]
        = (acch[reg] + accl[reg]) * inv;
  }
}

// ---------------------------------------------------------------------------
extern "C" void kernel_launch(void* const* d_in, const int* in_sizes, int n_in,
                              void* d_out, int out_size, void* d_ws, size_t ws_size,
                              hipStream_t stream) {
  const float* x   = (const float*)d_in[0];
  const int*   adj = (const int*)d_in[1];
  const float* ewt = (const float*)d_in[2];
  const float* W   = (const float*)d_in[3];
  const float* a   = (const float*)d_in[4];

  float* out = (float*)d_out;                  // [B,N,128]
  float* avg = out + (size_t)B * N * FO;       // [B,N,N]

  unsigned short* hhi = (unsigned short*)d_ws;        // [B*FO, N] bf16, 2 MB
  unsigned short* hlo = hhi + (size_t)B * FO * N;     // residual, 2 MB
  unsigned short* mew = hlo + (size_t)B * FO * N;     // [N,N] bf16 masked, 2 MB
  float* es   = (float*)(mew + (size_t)N * N);        // [B*N, 4]
  float* edt  = es + (size_t)B * N * NH;              // [B, 4, N]
  float* dinv = edt + (size_t)B * NH * N;             // [B*N, 4]

  gat_mask<<<(N * N) / 2048, 256, 0, stream>>>(adj, ewt, mew);
  gat_proj<<<(B * N) / 16, 256, 0, stream>>>(x, W, a, hhi, hlo, es, edt);
  gat_denom_avg<<<B * (N / 4), 256, 0, stream>>>(es, edt, mew, dinv, avg);
  gat_attn<<<B * (N / 16), 512, 0, stream>>>(hhi, hlo, es, edt, mew, dinv, out);
}

// Round 9
// 153.865 us; speedup vs baseline: 1.0771x; 1.0104x over previous
//
#include <hip/hip_runtime.h>
#include <hip/hip_bf16.h>

constexpr int B  = 8;
constexpr int N  = 1024;
constexpr int FI = 64;
constexpr int FO = 128;
constexpr int NH = 4;
constexpr float LOG2E = 1.4426950408889634f;

using short8 = __attribute__((ext_vector_type(8))) short;
using f32x4  = __attribute__((ext_vector_type(4))) float;

union I8 { int4 v[2]; int s[8]; };
union F8 { float4 v[2]; float s[8]; };

__device__ __forceinline__ unsigned bfpack(float a, float b) {
  __hip_bfloat162 r = __float22bfloat162_rn(make_float2(a, b));
  union { __hip_bfloat162 h; unsigned u; } c; c.h = r; return c.u;
}
__device__ __forceinline__ float bf2f(unsigned short u) {
  union { unsigned int b; float f; } c; c.b = (unsigned int)u << 16; return c.f;
}

// ---------------------------------------------------------------------------
// Kernel 0: mew[i][j] = adj ? bf16(ew) : -0.0  (sign bit = mask).
// ---------------------------------------------------------------------------
__global__ __launch_bounds__(256) void gat_mask(
    const int* __restrict__ adj, const float* __restrict__ ew,
    unsigned short* __restrict__ mew) {
  const size_t base = ((size_t)blockIdx.x * 256 + threadIdx.x) * 8;
  I8 aj; aj.v[0] = *(const int4*)(adj + base); aj.v[1] = *(const int4*)(adj + base + 4);
  F8 e;  e.v[0]  = *(const float4*)(ew + base); e.v[1]  = *(const float4*)(ew + base + 4);
  union { unsigned short u[8]; uint4 v; } o;
  #pragma unroll
  for (int u = 0; u < 8; ++u) {
    __hip_bfloat16 hb = __float2bfloat16(e.s[u]);
    unsigned short bits = *reinterpret_cast<unsigned short*>(&hb);
    o.u[u] = aj.s[u] ? bits : (unsigned short)0x8000;   // -0.0 when masked
  }
  *(uint4*)(mew + base) = o.v;
}

// ---------------------------------------------------------------------------
// Kernel 1: h = x@W. Emits es (row-major) + edt transposed [b][h][j] (both
// pre-scaled by log2e), and h transposed bf16 hi/lo: h_t[b][f][j].
// ---------------------------------------------------------------------------
__global__ __launch_bounds__(256, 2) void gat_proj(
    const float* __restrict__ x, const float* __restrict__ W,
    const float* __restrict__ a,
    unsigned short* __restrict__ h_hi, unsigned short* __restrict__ h_lo,
    float* __restrict__ es, float* __restrict__ edt) {
  __shared__ float xs[16 * FI];
  const int t = threadIdx.x;
  const int row0 = blockIdx.x * 16;
  for (int i = t; i < 16 * FI; i += 256) xs[i] = x[row0 * FI + i];
  const int f  = t & 127;
  const int rh = t >> 7;
  float wc[FI];
  #pragma unroll
  for (int k = 0; k < FI; ++k) wc[k] = W[k * FO + f];
  const int hh = f >> 5, d = f & 31;
  const float a_s = a[hh * 64 + d] * LOG2E;
  const float a_d = a[hh * 64 + 32 + d] * LOG2E;
  __syncthreads();
  float acc8[8];
  #pragma unroll
  for (int r = 0; r < 8; ++r) {
    const int lr = rh * 8 + r;
    const float4* xr = (const float4*)(xs + lr * FI);
    float acc = 0.f;
    #pragma unroll
    for (int kq = 0; kq < FI / 4; ++kq) {
      const float4 xv = xr[kq];
      acc += xv.x * wc[4*kq] + xv.y * wc[4*kq+1] + xv.z * wc[4*kq+2] + xv.w * wc[4*kq+3];
    }
    acc8[r] = acc;
    float ps = acc * a_s, pd = acc * a_d;
    #pragma unroll
    for (int off = 16; off; off >>= 1) {
      ps += __shfl_xor(ps, off, 64);
      pd += __shfl_xor(pd, off, 64);
    }
    const int row = row0 + lr;
    if (d == 0) {
      es[row * NH + hh] = ps;
      edt[((size_t)((row >> 10) * NH + hh)) * N + (row & 1023)] = pd;
    }
  }
  const int bb = row0 >> 10;
  const int jl = (row0 & 1023) + rh * 8;
  union { unsigned short u16[8]; uint4 v; } hi, lo;
  #pragma unroll
  for (int r = 0; r < 8; ++r) {
    __hip_bfloat16 hb = __float2bfloat16(acc8[r]);
    hi.u16[r] = *reinterpret_cast<unsigned short*>(&hb);
    float res = acc8[r] - __bfloat162float(hb);
    __hip_bfloat16 lb = __float2bfloat16(res);
    lo.u16[r] = *reinterpret_cast<unsigned short*>(&lb);
  }
  const size_t base = ((size_t)(bb * FO + f)) * N + jl;
  *(uint4*)(h_hi + base) = hi.v;
  *(uint4*)(h_lo + base) = lo.v;
}

// ---------------------------------------------------------------------------
// Kernel 1b: denominators + avg, fused. 2048 blocks (8/CU), 4 rows/block,
// one wave per row, no LDS/barriers. (256,4): 128-VGPR cap so loads pipeline.
// ---------------------------------------------------------------------------
__global__ __launch_bounds__(256, 4) void gat_denom_avg(
    const float* __restrict__ es, const float* __restrict__ edt,
    const unsigned short* __restrict__ mew, float* __restrict__ dinv,
    float* __restrict__ avg) {
  const int t  = threadIdx.x;
  const int b  = blockIdx.x & 7;
  const int i0 = (blockIdx.x >> 3) << 2;     // 4 rows/block
  const int il = t >> 6, jq = t & 63;
  const int gi = i0 + il;
  float esv[4];
  { const float4 e4 = *(const float4*)(es + ((size_t)b * N + gi) * NH);
    esv[0] = e4.x; esv[1] = e4.y; esv[2] = e4.z; esv[3] = e4.w; }
  // ---- pass 1: denominators ----
  float dpart[4] = {0.f, 0.f, 0.f, 0.f};
  #pragma unroll
  for (int c = 0; c < 4; ++c) {
    const int jb = c * 256 + jq * 4;
    union { uint2 v; unsigned short u[4]; } mw;
    mw.v = *(const uint2*)(mew + (size_t)gi * N + jb);
    float edh[4][4];
    #pragma unroll
    for (int h = 0; h < 4; ++h) {
      const float4 e4 = *(const float4*)(edt + ((size_t)(b * NH + h)) * N + jb);
      edh[h][0] = e4.x; edh[h][1] = e4.y; edh[h][2] = e4.z; edh[h][3] = e4.w;
    }
    #pragma unroll
    for (int u = 0; u < 4; ++u) {
      const float sgn = (mw.u[u] >> 15) ? 0.f : 1.f;
      #pragma unroll
      for (int h = 0; h < 4; ++h) {
        float e = esv[h] + edh[h][u];
        e = fmaxf(e, 0.2f * e);
        dpart[h] = fmaf(__builtin_amdgcn_exp2f(e), sgn, dpart[h]);
      }
    }
  }
  float inv4[4];
  #pragma unroll
  for (int h = 0; h < 4; ++h) {
    float v = dpart[h];
    v += __shfl_xor(v, 1, 64);  v += __shfl_xor(v, 2, 64);
    v += __shfl_xor(v, 4, 64);  v += __shfl_xor(v, 8, 64);
    v += __shfl_xor(v, 16, 64); v += __shfl_xor(v, 32, 64);
    inv4[h] = v > 0.f ? 1.0f / v : 0.f;
  }
  if (jq == 0)
    *(float4*)(dinv + ((size_t)b * N + gi) * NH)
        = make_float4(inv4[0], inv4[1], inv4[2], inv4[3]);
  // ---- pass 2: avg (loads L1-hot from pass 1) ----
  #pragma unroll
  for (int c = 0; c < 4; ++c) {
    const int jb = c * 256 + jq * 4;
    union { uint2 v; unsigned short u[4]; } mw;
    mw.v = *(const uint2*)(mew + (size_t)gi * N + jb);
    float edh[4][4];
    #pragma unroll
    for (int h = 0; h < 4; ++h) {
      const float4 e4 = *(const float4*)(edt + ((size_t)(b * NH + h)) * N + jb);
      edh[h][0] = e4.x; edh[h][1] = e4.y; edh[h][2] = e4.z; edh[h][3] = e4.w;
    }
    float4 r;
    float* rp = &r.x;
    #pragma unroll
    for (int u = 0; u < 4; ++u) {
      const float mfa = bf2f((unsigned short)(mw.u[u] & 0x7fff));
      float sv = 0.f;
      #pragma unroll
      for (int h = 0; h < 4; ++h) {
        float e = esv[h] + edh[h][u];
        e = fmaxf(e, 0.2f * e);
        sv += __builtin_amdgcn_exp2f(e) * inv4[h];
      }
      rp[u] = 0.25f * mfa * sv;            // masked: mfa=0 -> 0
    }
    *(float4*)(avg + ((size_t)b * N + gi) * N + jb) = r;
  }
}

// ---------------------------------------------------------------------------
// Kernel 2: attention out. ZERO LDS/barriers (R8 structure) + EXPLICIT
// 2-deep load prefetch with fully-unrolled K-loop. (512,2): 256-VGPR cap
// so the 3 in-flight load sets (~60 VGPR) live in registers and vmcnt
// waits split per-set instead of serializing each step. [R8: VGPR=28,
// VALUBusy 28% - compiler refused to pipeline under the 64-reg cap.]
// ---------------------------------------------------------------------------
__global__ __launch_bounds__(512, 2) void gat_attn(
    const unsigned short* __restrict__ h_hi, const unsigned short* __restrict__ h_lo,
    const float* __restrict__ es, const float* __restrict__ edt,
    const unsigned short* __restrict__ mew, const float* __restrict__ dinv,
    float* __restrict__ out) {
  const int t  = threadIdx.x;
  const int b  = blockIdx.x & 7;              // b-clustered for h_t L2 locality
  const int i0 = (blockIdx.x >> 3) << 4;      // 16-row tile
  const int lane = t & 63, wave = t >> 6;
  const int hh = wave & 3, nt2 = wave >> 2;
  const int m = lane & 15, kq = lane >> 4;
  const int gi = i0 + m;
  const float esv = es[((size_t)b * N + gi) * NH + hh];
  const unsigned short* mrow = mew + (size_t)gi * N + kq * 8;
  const float*          erow = edt + ((size_t)(b * NH + hh)) * N + kq * 8;
  const size_t hoff = ((size_t)(b * FO + hh * 32 + nt2 * 16 + m)) * N + kq * 8;
  const unsigned short* hrow_hi = h_hi + hoff;
  const unsigned short* hrow_lo = h_lo + hoff;
  f32x4 acch = {0.f,0.f,0.f,0.f}, accl = {0.f,0.f,0.f,0.f};

  struct Frag { uint4 mw; float4 e0, e1; short8 bhi, blo; };
  auto ldf = [&](int s) {
    Frag f;
    const int j = s * 32;
    f.mw  = *(const uint4*)(mrow + j);
    f.e0  = *(const float4*)(erow + j);
    f.e1  = *(const float4*)(erow + j + 4);
    f.bhi = *(const short8*)(hrow_hi + j);
    f.blo = *(const short8*)(hrow_lo + j);
    return f;
  };
  auto step = [&](const Frag& f) {
    union { uint4 v; unsigned short u[8]; } mw; mw.v = f.mw;
    const float ed8[8] = {f.e0.x, f.e0.y, f.e0.z, f.e0.w,
                          f.e1.x, f.e1.y, f.e1.z, f.e1.w};
    float pw[8];
    #pragma unroll
    for (int u = 0; u < 8; ++u) {
      float e = esv + ed8[u];
      e = fmaxf(e, 0.2f * e);
      pw[u] = __builtin_amdgcn_exp2f(e)
            * bf2f((unsigned short)(mw.u[u] & 0x7fff));   // masked -> 0
    }
    union { unsigned u[4]; short8 s8; } af;
    af.u[0] = bfpack(pw[0], pw[1]); af.u[1] = bfpack(pw[2], pw[3]);
    af.u[2] = bfpack(pw[4], pw[5]); af.u[3] = bfpack(pw[6], pw[7]);
    acch = __builtin_amdgcn_mfma_f32_16x16x32_bf16(af.s8, f.bhi, acch, 0, 0, 0);
    accl = __builtin_amdgcn_mfma_f32_16x16x32_bf16(af.s8, f.blo, accl, 0, 0, 0);
  };

  // software pipeline: 2-deep prefetch, fully unrolled (rotation regs are SSA)
  Frag f0 = ldf(0);
  Frag f1 = ldf(1);
  #pragma unroll
  for (int s = 0; s < 32; ++s) {
    Frag fn;
    if (s + 2 < 32) fn = ldf(s + 2);
    step(f0);
    f0 = f1;
    f1 = fn;
  }

  #pragma unroll
  for (int reg = 0; reg < 4; ++reg) {
    const int row = kq * 4 + reg;              // D: col=lane&15, row=quad*4+reg
    const float inv = dinv[((size_t)b * N + i0 + row) * NH + hh];
    out[((size_t)b * N + i0 + row) * FO + hh * 32 + nt2 * 16 + m]
        = (acch[reg] + accl[reg]) * inv;
  }
}

// ---------------------------------------------------------------------------
extern "C" void kernel_launch(void* const* d_in, const int* in_sizes, int n_in,
                              void* d_out, int out_size, void* d_ws, size_t ws_size,
                              hipStream_t stream) {
  const float* x   = (const float*)d_in[0];
  const int*   adj = (const int*)d_in[1];
  const float* ewt = (const float*)d_in[2];
  const float* W   = (const float*)d_in[3];
  const float* a   = (const float*)d_in[4];

  float* out = (float*)d_out;                  // [B,N,128]
  float* avg = out + (size_t)B * N * FO;       // [B,N,N]

  unsigned short* hhi = (unsigned short*)d_ws;        // [B*FO, N] bf16, 2 MB
  unsigned short* hlo = hhi + (size_t)B * FO * N;     // residual, 2 MB
  unsigned short* mew = hlo + (size_t)B * FO * N;     // [N,N] bf16 masked, 2 MB
  float* es   = (float*)(mew + (size_t)N * N);        // [B*N, 4]
  float* edt  = es + (size_t)B * N * NH;              // [B, 4, N]
  float* dinv = edt + (size_t)B * NH * N;             // [B*N, 4]

  gat_mask<<<(N * N) / 2048, 256, 0, stream>>>(adj, ewt, mew);
  gat_proj<<<(B * N) / 16, 256, 0, stream>>>(x, W, a, hhi, hlo, es, edt);
  gat_denom_avg<<<B * (N / 4), 256, 0, stream>>>(es, edt, mew, dinv, avg);
  gat_attn<<<B * (N / 16), 512, 0, stream>>>(hhi, hlo, es, edt, mew, dinv, out);
}

// Round 10
// 115.386 us; speedup vs baseline: 1.4363x; 1.3335x over previous
//
#include <hip/hip_runtime.h>
#include <hip/hip_bf16.h>

constexpr int B  = 8;
constexpr int N  = 1024;
constexpr int FI = 64;
constexpr int FO = 128;
constexpr int NH = 4;
constexpr float LOG2E = 1.4426950408889634f;

using short8 = __attribute__((ext_vector_type(8))) short;
using f32x4  = __attribute__((ext_vector_type(4))) float;

union I8 { int4 v[2]; int s[8]; };
union F8 { float4 v[2]; float s[8]; };

__device__ __forceinline__ unsigned bfpack(float a, float b) {
  __hip_bfloat162 r = __float22bfloat162_rn(make_float2(a, b));
  union { __hip_bfloat162 h; unsigned u; } c; c.h = r; return c.u;
}
__device__ __forceinline__ float bf2f(unsigned short u) {
  union { unsigned int b; float f; } c; c.b = (unsigned int)u << 16; return c.f;
}

// ---------------------------------------------------------------------------
// Kernel 0: mew[i][j] = adj ? bf16(ew) : -0.0  (sign bit = mask).
// ---------------------------------------------------------------------------
__global__ __launch_bounds__(256) void gat_mask(
    const int* __restrict__ adj, const float* __restrict__ ew,
    unsigned short* __restrict__ mew) {
  const size_t base = ((size_t)blockIdx.x * 256 + threadIdx.x) * 8;
  I8 aj; aj.v[0] = *(const int4*)(adj + base); aj.v[1] = *(const int4*)(adj + base + 4);
  F8 e;  e.v[0]  = *(const float4*)(ew + base); e.v[1]  = *(const float4*)(ew + base + 4);
  union { unsigned short u[8]; uint4 v; } o;
  #pragma unroll
  for (int u = 0; u < 8; ++u) {
    __hip_bfloat16 hb = __float2bfloat16(e.s[u]);
    unsigned short bits = *reinterpret_cast<unsigned short*>(&hb);
    o.u[u] = aj.s[u] ? bits : (unsigned short)0x8000;   // -0.0 when masked
  }
  *(uint4*)(mew + base) = o.v;
}

// ---------------------------------------------------------------------------
// Kernel 1: h = x@W. Emits es (row-major) + edt transposed [b][h][j] (both
// pre-scaled by log2e), and h in PRE-FRAGMENTED MFMA-B layout, bf16 hi/lo:
//   hfrag[b][ft(8)][s(32)][lane(64)][8]   (lane = n + 16*kq, j = s*32+kq*8+u)
// so attn's per-wave B-load is ONE contiguous 1KB segment per K-step.
// ---------------------------------------------------------------------------
__global__ __launch_bounds__(256, 2) void gat_proj(
    const float* __restrict__ x, const float* __restrict__ W,
    const float* __restrict__ a,
    unsigned short* __restrict__ h_hi, unsigned short* __restrict__ h_lo,
    float* __restrict__ es, float* __restrict__ edt) {
  __shared__ float xs[16 * FI];
  const int t = threadIdx.x;
  const int row0 = blockIdx.x * 16;
  for (int i = t; i < 16 * FI; i += 256) xs[i] = x[row0 * FI + i];
  const int f  = t & 127;
  const int rh = t >> 7;
  float wc[FI];
  #pragma unroll
  for (int k = 0; k < FI; ++k) wc[k] = W[k * FO + f];
  const int hh = f >> 5, d = f & 31;
  const float a_s = a[hh * 64 + d] * LOG2E;
  const float a_d = a[hh * 64 + 32 + d] * LOG2E;
  __syncthreads();
  float acc8[8];
  #pragma unroll
  for (int r = 0; r < 8; ++r) {
    const int lr = rh * 8 + r;
    const float4* xr = (const float4*)(xs + lr * FI);
    float acc = 0.f;
    #pragma unroll
    for (int kq = 0; kq < FI / 4; ++kq) {
      const float4 xv = xr[kq];
      acc += xv.x * wc[4*kq] + xv.y * wc[4*kq+1] + xv.z * wc[4*kq+2] + xv.w * wc[4*kq+3];
    }
    acc8[r] = acc;
    float ps = acc * a_s, pd = acc * a_d;
    #pragma unroll
    for (int off = 16; off; off >>= 1) {
      ps += __shfl_xor(ps, off, 64);
      pd += __shfl_xor(pd, off, 64);
    }
    const int row = row0 + lr;
    if (d == 0) {
      es[row * NH + hh] = ps;
      edt[((size_t)((row >> 10) * NH + hh)) * N + (row & 1023)] = pd;
    }
  }
  const int bb = row0 >> 10;
  const int jl = (row0 & 1023) + rh * 8;       // 8 consecutive j, 8-aligned
  union { unsigned short u16[8]; uint4 v; } hi, lo;
  #pragma unroll
  for (int r = 0; r < 8; ++r) {
    __hip_bfloat16 hb = __float2bfloat16(acc8[r]);
    hi.u16[r] = *reinterpret_cast<unsigned short*>(&hb);
    float res = acc8[r] - __bfloat162float(hb);
    __hip_bfloat16 lb = __float2bfloat16(res);
    lo.u16[r] = *reinterpret_cast<unsigned short*>(&lb);
  }
  // B-fragment address: ft = f>>4, n = f&15, s = jl>>5, kq = (jl>>3)&3
  const int ft = f >> 4, n = f & 15;
  const int sS = jl >> 5, kq2 = (jl >> 3) & 3;
  const size_t base = (size_t)bb * (FO * N)
                    + ((size_t)(ft * 32 + sS) * 64 + (n + 16 * kq2)) * 8;
  *(uint4*)(h_hi + base) = hi.v;
  *(uint4*)(h_lo + base) = lo.v;
}

// ---------------------------------------------------------------------------
// Kernel 2: attention out (+ dinv). 512 thr, 16-row tiles, 512 blocks.
// Single pass over 8 chunks of 128 j, double-buffered pew, 1 barrier/chunk:
//  P1(c+1): 16 exps -> pw = p*|mew| bf16 -> pew LDS; dpart += p*sgn.
//  B-prefetch(c+1): 8 contiguous 1KB wave loads (hfrag layout) -> regs;
//     the barrier's vmcnt drain completes them during P1+barrier.
//  P2(c): ds_read A-frags + MFMA with B already in registers (4 indep chains).
// Epilogue: dpart shuffle+LDS reduce -> inv; write dinv global; out = acc*inv.
// ---------------------------------------------------------------------------
__global__ __launch_bounds__(512, 2) void gat_attn(
    const unsigned short* __restrict__ h_hi, const unsigned short* __restrict__ h_lo,
    const float* __restrict__ es, const float* __restrict__ edt,
    const unsigned short* __restrict__ mew,
    float* __restrict__ out, float* __restrict__ dinv) {
  __shared__ unsigned short pew[2][4 * 2048];
  __shared__ float dvl[64];
  const int t  = threadIdx.x;
  const int b  = blockIdx.x & 7;
  const int i0 = (blockIdx.x >> 3) << 4;
  // P1 ids
  const int il = t >> 5, jq = t & 31;
  const int gi = i0 + il;
  float esv[4];
  { const float4 e4 = *(const float4*)(es + ((size_t)b * N + gi) * NH);
    esv[0] = e4.x; esv[1] = e4.y; esv[2] = e4.z; esv[3] = e4.w; }
  // P2 ids
  const int lane = t & 63, wave = t >> 6;
  const int hh = wave & 3, nt2 = wave >> 2;
  const int m = lane & 15, kq = lane >> 4;
  const int ft = hh * 2 + nt2;
  const unsigned short* hb_hi = h_hi + (size_t)b * (FO * N) + (size_t)(ft * 32) * 512 + lane * 8;
  const unsigned short* hb_lo = h_lo + (size_t)b * (FO * N) + (size_t)(ft * 32) * 512 + lane * 8;
  f32x4 acc0 = {0.f,0.f,0.f,0.f}, acc1 = {0.f,0.f,0.f,0.f};
  f32x4 acc2 = {0.f,0.f,0.f,0.f}, acc3 = {0.f,0.f,0.f,0.f};
  float dpart[4] = {0.f, 0.f, 0.f, 0.f};

  auto p1_step = [&](int c, int buf) {
    const int jb = c * 128 + jq * 4;
    union { unsigned v2[2]; unsigned short u[4]; } mw;
    *(uint2*)mw.v2 = *(const uint2*)(mew + (size_t)gi * N + jb);
    float edh[4][4];
    #pragma unroll
    for (int h = 0; h < 4; ++h) {
      const float4 e4 = *(const float4*)(edt + ((size_t)(b * NH + h)) * N + jb);
      edh[h][0] = e4.x; edh[h][1] = e4.y; edh[h][2] = e4.z; edh[h][3] = e4.w;
    }
    float pw[4][4];
    #pragma unroll
    for (int u = 0; u < 4; ++u) {
      const float mfa = bf2f((unsigned short)(mw.u[u] & 0x7fff));
      const float sgn = (mw.u[u] >> 15) ? 0.f : 1.f;
      #pragma unroll
      for (int h = 0; h < 4; ++h) {
        float e = esv[h] + edh[h][u];
        e = fmaxf(e, 0.2f * e);
        const float p = __builtin_amdgcn_exp2f(e);
        pw[h][u] = p * mfa;                     // masked: mfa=0 -> 0
        dpart[h] = fmaf(p, sgn, dpart[h]);
      }
    }
    const int g = jq >> 1, half = jq & 1;
    const int o = ((g * 16 + il) ^ (g & 7)) * 8 + half * 4;
    #pragma unroll
    for (int h = 0; h < 4; ++h) {
      uint2 pk = { bfpack(pw[h][0], pw[h][1]), bfpack(pw[h][2], pw[h][3]) };
      *(uint2*)(pew[buf] + h * 2048 + o) = pk;
    }
  };

  short8 Bh[4], Bl[4];
  // preload chunk 0 B-frags (contiguous 1KB wave segments)
  #pragma unroll
  for (int ks = 0; ks < 4; ++ks) {
    Bh[ks] = *(const short8*)(hb_hi + (size_t)ks * 512);
    Bl[ks] = *(const short8*)(hb_lo + (size_t)ks * 512);
  }
  p1_step(0, 0);
  __syncthreads();

  for (int c = 0; c < 8; ++c) {
    short8 Ph[4], Pl[4];
    if (c + 1 < 8) {
      p1_step(c + 1, (c + 1) & 1);
      const size_t so = (size_t)(c + 1) * 4 * 512;
      #pragma unroll
      for (int ks = 0; ks < 4; ++ks) {
        Ph[ks] = *(const short8*)(hb_hi + so + (size_t)ks * 512);
        Pl[ks] = *(const short8*)(hb_lo + so + (size_t)ks * 512);
      }
    }
    // ---- P2: A from LDS, B already in registers ----
    {
      const int buf = c & 1;
      #pragma unroll
      for (int ks = 0; ks < 4; ++ks) {
        const int g2 = ks * 4 + kq;
        const int o2 = ((g2 * 16 + m) ^ (g2 & 7)) * 8;
        short8 afr;
        { uint4 tmp = *(const uint4*)(pew[buf] + hh * 2048 + o2);
          __builtin_memcpy(&afr, &tmp, 16); }
        if (ks & 1) {
          acc2 = __builtin_amdgcn_mfma_f32_16x16x32_bf16(afr, Bh[ks], acc2, 0, 0, 0);
          acc3 = __builtin_amdgcn_mfma_f32_16x16x32_bf16(afr, Bl[ks], acc3, 0, 0, 0);
        } else {
          acc0 = __builtin_amdgcn_mfma_f32_16x16x32_bf16(afr, Bh[ks], acc0, 0, 0, 0);
          acc1 = __builtin_amdgcn_mfma_f32_16x16x32_bf16(afr, Bl[ks], acc1, 0, 0, 0);
        }
      }
    }
    if (c + 1 < 8) __syncthreads();
    #pragma unroll
    for (int ks = 0; ks < 4; ++ks) { Bh[ks] = Ph[ks]; Bl[ks] = Pl[ks]; }
  }

  // ---- denominators: reduce over the 32-lane half sharing il ----
  #pragma unroll
  for (int h = 0; h < 4; ++h) {
    float v = dpart[h];
    v += __shfl_xor(v, 1, 64);  v += __shfl_xor(v, 2, 64);
    v += __shfl_xor(v, 4, 64);  v += __shfl_xor(v, 8, 64);
    v += __shfl_xor(v, 16, 64);
    if (jq == 0) dvl[il * NH + h] = v;
  }
  __syncthreads();
  if (t < 64) { const float dd = dvl[t]; dvl[t] = dd > 0.f ? 1.0f / dd : 0.f; }
  __syncthreads();
  if (t < 64) dinv[((size_t)b * N + i0) * NH + t] = dvl[t];
  // ---- out = (acc_hi + acc_lo) * inv  (fp32, R4-proven) ----
  #pragma unroll
  for (int reg = 0; reg < 4; ++reg) {
    const int row = kq * 4 + reg;              // D: col=lane&15, row=quad*4+reg
    const float inv = dvl[row * NH + hh];
    out[((size_t)b * N + i0 + row) * FO + hh * 32 + nt2 * 16 + m]
        = (acc0[reg] + acc1[reg] + acc2[reg] + acc3[reg]) * inv;
  }
}

// ---------------------------------------------------------------------------
// Kernel 3: avg. 2048 blocks (8/CU), 4 rows/block, one wave per row,
// no LDS/barriers. Recompute p, scale by dinv (R9-proven numerics),
// coalesced float4 writes. Write-bound: ~33.5 MB.
// ---------------------------------------------------------------------------
__global__ __launch_bounds__(256, 4) void gat_avg(
    const float* __restrict__ es, const float* __restrict__ edt,
    const unsigned short* __restrict__ mew, const float* __restrict__ dinv,
    float* __restrict__ avg) {
  const int t  = threadIdx.x;
  const int b  = blockIdx.x & 7;
  const int i0 = (blockIdx.x >> 3) << 2;
  const int il = t >> 6, jq = t & 63;
  const int gi = i0 + il;
  float esv[4], inv4[4];
  { const float4 e4 = *(const float4*)(es + ((size_t)b * N + gi) * NH);
    esv[0] = e4.x; esv[1] = e4.y; esv[2] = e4.z; esv[3] = e4.w; }
  { const float4 d4 = *(const float4*)(dinv + ((size_t)b * N + gi) * NH);
    inv4[0] = d4.x; inv4[1] = d4.y; inv4[2] = d4.z; inv4[3] = d4.w; }
  #pragma unroll
  for (int c = 0; c < 4; ++c) {
    const int jb = c * 256 + jq * 4;
    union { uint2 v; unsigned short u[4]; } mw;
    mw.v = *(const uint2*)(mew + (size_t)gi * N + jb);
    float edh[4][4];
    #pragma unroll
    for (int h = 0; h < 4; ++h) {
      const float4 e4 = *(const float4*)(edt + ((size_t)(b * NH + h)) * N + jb);
      edh[h][0] = e4.x; edh[h][1] = e4.y; edh[h][2] = e4.z; edh[h][3] = e4.w;
    }
    float4 r;
    float* rp = &r.x;
    #pragma unroll
    for (int u = 0; u < 4; ++u) {
      const float mfa = bf2f((unsigned short)(mw.u[u] & 0x7fff));
      float sv = 0.f;
      #pragma unroll
      for (int h = 0; h < 4; ++h) {
        float e = esv[h] + edh[h][u];
        e = fmaxf(e, 0.2f * e);
        sv += __builtin_amdgcn_exp2f(e) * inv4[h];
      }
      rp[u] = 0.25f * mfa * sv;            // masked: mfa=0 -> 0
    }
    *(float4*)(avg + ((size_t)b * N + gi) * N + jb) = r;
  }
}

// ---------------------------------------------------------------------------
extern "C" void kernel_launch(void* const* d_in, const int* in_sizes, int n_in,
                              void* d_out, int out_size, void* d_ws, size_t ws_size,
                              hipStream_t stream) {
  const float* x   = (const float*)d_in[0];
  const int*   adj = (const int*)d_in[1];
  const float* ewt = (const float*)d_in[2];
  const float* W   = (const float*)d_in[3];
  const float* a   = (const float*)d_in[4];

  float* out = (float*)d_out;                  // [B,N,128]
  float* avg = out + (size_t)B * N * FO;       // [B,N,N]

  unsigned short* hhi = (unsigned short*)d_ws;        // hfrag hi, 2 MB
  unsigned short* hlo = hhi + (size_t)B * FO * N;     // hfrag lo, 2 MB
  unsigned short* mew = hlo + (size_t)B * FO * N;     // [N,N] bf16 masked, 2 MB
  float* es   = (float*)(mew + (size_t)N * N);        // [B*N, 4]
  float* edt  = es + (size_t)B * N * NH;              // [B, 4, N]
  float* dnv  = edt + (size_t)B * NH * N;             // [B*N, 4]

  gat_mask<<<(N * N) / 2048, 256, 0, stream>>>(adj, ewt, mew);
  gat_proj<<<(B * N) / 16, 256, 0, stream>>>(x, W, a, hhi, hlo, es, edt);
  gat_attn<<<B * (N / 16), 512, 0, stream>>>(hhi, hlo, es, edt, mew, out, dnv);
  gat_avg<<<B * (N / 4), 256, 0, stream>>>(es, edt, mew, dnv, avg);
}